// Round 20
// baseline (1676.300 us; speedup 1.0000x reference)
//
#include <hip/hip_runtime.h>
#include <math.h>

#define BATCH 16
#define LPH 128
#define TFR 1024
#define DMODEL 384
#define FDIM 1536
#define NLAYER 6
#define NMELB 80
#define CDPC 256
#define NEGV (-1e9f)

typedef unsigned short u16;
typedef __attribute__((ext_vector_type(8))) short short8;
typedef __attribute__((ext_vector_type(4))) float f32x4;

__device__ __forceinline__ float b2f(u16 u) {
  return __uint_as_float(((unsigned)u) << 16);
}
__device__ __forceinline__ u16 f2b(float f) {
  unsigned x = __float_as_uint(f);
  return (u16)((x + 0x7fffu + ((x >> 16) & 1u)) >> 16);
}
// pack 2 f32 -> 2 bf16 in one HW op (no builtin on gfx950; inline asm per T12)
__device__ __forceinline__ unsigned cvtpk(float lo, float hi) {
  unsigned r;
  asm volatile("v_cvt_pk_bf16_f32 %0, %1, %2" : "=v"(r) : "v"(lo), "v"(hi));
  return r;
}

#define GLOAD16(gp, lp)                                                                   \
  __builtin_amdgcn_global_load_lds((const __attribute__((address_space(1))) void*)(gp),   \
                                   (__attribute__((address_space(3))) void*)(lp), 16, 0, 0)

#define FBIAS 1
#define FRES 2
#define FRELU 4
#define FOB16 8
#define FVT 16

// ===================== bf16 MFMA GEMM, 128x128 tile ==========================
// 2-PHASE double-buffered, BK=32 (T3-minimum): per iteration, issue next tile's
// global_load_lds into buf^1, compute current buf, ONE barrier (drain overlaps
// the compute phase instead of being adjacent to the issue). LDS = 4 x 8 KB =
// 32 KB (same occupancy as R17-19 single-buffer BK=64).
// Bank layout per buffer: [64 row-pairs][64 u16], slot = ((row&1)*4|lk)^(p&7)
// -> 2-way alias on fragment reads; staging source pre-swizzled globally so
// the gload_lds LDS destination stays lane-linear (rule #21). K % 32 == 0.
// XCD-aware tile remap; split-K via z; FVT: LDS-transposed Vt store (Ts
// overlays the buffers after the final barrier).
#define DSW(p, hl) ((p) * 64 + ((hl) ^ ((p)&7)) * 8)
template <int FL>
__global__ __launch_bounds__(256) void bgemm(
    const u16* __restrict__ A, const u16* __restrict__ Bt,
    const float* __restrict__ bias, const float* __restrict__ res,
    void* __restrict__ Cv, u16* __restrict__ VtP,
    int N, int K, int lda, int ldb, int ldc,
    int zdiv, long az0, long az1, long bz0, long bz1, long cz0, long cz1, int S) {
  constexpr int SMEMSZ = (FL & FVT) ? (128 * 136) : 16384;
  __shared__ __align__(16) u16 smem[SMEMSZ];
  const int tid = threadIdx.x;
  const int wave = tid >> 6, lane = tid & 63;
  const int wm = wave >> 1, wn = wave & 1;
  const int lrow = lane & 15, lk = lane >> 4;
  const int z = blockIdx.z;
  const int zq = z / zdiv, zr = z - zq * zdiv;
  const long offA = (long)zq * az0 + (long)zr * az1;
  const long offB = (long)zq * bz0 + (long)zr * bz1;
  const long offC = (long)zq * cz0 + (long)zr * cz1;
  const int fid = blockIdx.x + gridDim.x * blockIdx.y;
  const int idx = fid >> 3;
  const int xl = idx % gridDim.x;
  const int yl = (fid & 7) + 8 * (idx / gridDim.x);
  const int row0 = yl * 128;
  const int col0 = xl * 128;

  // staging: 512 16B-chunks per matrix per tile; 2 A + 2 B chunks per thread.
  // LDS dest linear in chunk index c; global source pre-swizzled:
  // p=c>>3, s=c&7, u=s^(p&7) -> global row 2p+(u>>2), k-chunk u&3.
  const u16* gA[2];
  const u16* gB[2];
  int lofs[2];
#pragma unroll
  for (int i = 0; i < 2; i++) {
    int c = tid + i * 256;
    int p = c >> 3, s = c & 7, u = s ^ (p & 7);
    int grow = 2 * p + (u >> 2), gcol = (u & 3) * 8;
    gA[i] = A + offA + (long)(row0 + grow) * lda + gcol;
    gB[i] = Bt + offB + (long)(col0 + grow) * ldb + gcol;
    lofs[i] = c * 8;
  }

  f32x4 acc[4][4];
  const f32x4 zero4 = {0.f, 0.f, 0.f, 0.f};
#pragma unroll
  for (int i = 0; i < 4; i++)
#pragma unroll
    for (int j = 0; j < 4; j++) acc[i][j] = zero4;

  // prologue: tile 0 -> buf 0
#pragma unroll
  for (int i = 0; i < 2; i++) {
    GLOAD16(gA[i], smem + lofs[i]);
    GLOAD16(gB[i], smem + 8192 + lofs[i]);
  }
#pragma unroll
  for (int i = 0; i < 2; i++) { gA[i] += 32; gB[i] += 32; }
  __syncthreads();

  const int nt = K >> 5;
  int cur = 0;
  for (int t = 0; t < nt; t++) {
    if (t + 1 < nt) {
      // issue next tile into buf^1: latency hides under this tile's compute
#pragma unroll
      for (int i = 0; i < 2; i++) {
        GLOAD16(gA[i], smem + (cur ^ 1) * 4096 + lofs[i]);
        GLOAD16(gB[i], smem + 8192 + (cur ^ 1) * 4096 + lofs[i]);
      }
#pragma unroll
      for (int i = 0; i < 2; i++) { gA[i] += 32; gB[i] += 32; }
    }
    short8 av[4], bv[4];
#pragma unroll
    for (int mi = 0; mi < 4; mi++) {
      int arow = wm * 64 + mi * 16 + lrow;
      av[mi] = *(const short8*)&smem[cur * 4096 + DSW(arow >> 1, ((arow & 1) << 2) | lk)];
    }
#pragma unroll
    for (int ni = 0; ni < 4; ni++) {
      int brow = wn * 64 + ni * 16 + lrow;
      bv[ni] = *(const short8*)&smem[8192 + cur * 4096 + DSW(brow >> 1, ((brow & 1) << 2) | lk)];
    }
#pragma unroll
    for (int mi = 0; mi < 4; mi++)
#pragma unroll
      for (int ni = 0; ni < 4; ni++)
        acc[mi][ni] = __builtin_amdgcn_mfma_f32_16x16x32_bf16(av[mi], bv[ni], acc[mi][ni], 0, 0, 0);
    __syncthreads();  // drains buf^1 loads (issued a full compute-phase ago) + syncs
    cur ^= 1;
  }

  const float* bz = (FL & FBIAS) ? bias + (long)z * N : nullptr;
  if constexpr ((FL & FVT) != 0) {
    if (z == 2) {
      u16* Ts = smem;  // overlays buffers (dead after final barrier)
#pragma unroll
      for (int mi = 0; mi < 4; mi++) {
        int si = wm * 64 + lk * 4 + mi * 16;
#pragma unroll
        for (int ni = 0; ni < 4; ni++) {
          int cl = wn * 64 + ni * 16 + lrow;
          float bi = bz[col0 + cl];
          uint2 oo;
          oo.x = cvtpk(acc[mi][ni][0] + bi, acc[mi][ni][1] + bi);
          oo.y = cvtpk(acc[mi][ni][2] + bi, acc[mi][ni][3] + bi);
          *(uint2*)&Ts[cl * 136 + si] = oo;
        }
      }
      __syncthreads();
      const int ci = tid >> 1;
      const int cbase = (tid & 1) * 64;
      int c = col0 + ci;
      int hh = c / 192, dd = c - hh * 192;
      int bb = row0 / S;
      int ss = row0 % S;
      u16* dst = &VtP[((long)(bb * 2 + hh) * 256 + dd) * S + ss + cbase];
      const u16* srcr = &Ts[ci * 136 + cbase];
#pragma unroll
      for (int j = 0; j < 8; j++)
        *(short8*)&dst[j * 8] = *(const short8*)&srcr[j * 8];
      return;
    }
  }
  float* Cf = (float*)Cv + offC;
  u16* Cb = (u16*)Cv + offC;
  const float* resz = (FL & FRES) ? res + offC : nullptr;
#pragma unroll
  for (int mi = 0; mi < 4; mi++) {
    long rbase = row0 + wm * 64 + lk * 4 + (long)mi * 16;
#pragma unroll
    for (int ni = 0; ni < 4; ni++) {
      int c = col0 + wn * 64 + ni * 16 + lrow;
      if (c < N) {
        float bi = (FL & FBIAS) ? bz[c] : 0.f;
#pragma unroll
        for (int rr = 0; rr < 4; rr++) {
          float vv = acc[mi][ni][rr] + bi;
          if (FL & FRES) vv += resz[(rbase + rr) * (long)ldc + c];
          if (FL & FRELU) vv = fmaxf(vv, 0.f);
          if (FL & FOB16) Cb[(rbase + rr) * (long)ldc + c] = f2b(vv);
          else Cf[(rbase + rr) * (long)ldc + c] = vv;
        }
      }
    }
  }
}

// ============ fused flash attention, split-K partials (bf16 MFMA) ============
// 8 waves x 16 q-rows = 128 q-rows/block (512 thr); KVBLK=64.
// LDS 70.7 KB -> 2 blocks/CU (grid is 2/CU anyway). Natural VGPR (88, no spill).
// grid (QT, 32, 2). SWAPPED QK^T; defer-max; cvt_pk; additive mask.
#define KSW(r, c) ((r) * 192 + ((c) ^ (((r)&7) << 3)))
#define VSTR 72
#define PSTR 72
__global__ __launch_bounds__(512) void fattn(const u16* __restrict__ qb,
                                             const u16* __restrict__ kb,
                                             const u16* __restrict__ vt,
                                             const float* __restrict__ maska,  // 0 / -1e9
                                             u16* __restrict__ opart,
                                             float* __restrict__ mlpart,
                                             int S, int qtshift) {
  __shared__ __align__(16) u16 Ks[64 * 192];        // 24 KB (XOR swizzle)
  __shared__ __align__(16) u16 Vs[192 * VSTR];      // 27.6 KB (pad stride 144B)
  __shared__ __align__(16) u16 PsT[8][16 * PSTR];   // 18.4 KB per-wave P^T
  const int tid = threadIdx.x;
  const int w = tid >> 6, l = tid & 63;
  const int g = l >> 4, lr = l & 15;
  const int QT = gridDim.x;
  const int fid = (blockIdx.z * 32 + blockIdx.y) * QT + blockIdx.x;
  const int s = fid >> 3;
  const int gid = (fid & 7) * 8 + (s >> qtshift);  // 8 locality groups per XCD
  const int qt = s & (QT - 1);
  const int bh = gid & 31, z = gid >> 5;
  const int b = bh >> 1, h = bh & 1;
  const int q0 = qt * 128 + w * 16;
  const int hoff = h * 192;
  const int KS = S >> 1;
  const int kbeg = z * KS;
  const float scale = 0.0721687836f;  // 1/sqrt(192)

  // staging: K tile 64x192 = 1536 chunks, V tile 192x64 = 1536 chunks; 6/thread
  int kr[3], kc[3], vr[3], vc[3];
#pragma unroll
  for (int i = 0; i < 3; i++) {
    int c = tid + i * 512;
    kr[i] = c / 24; kc[i] = (c % 24) * 8;
    vr[i] = c >> 3; vc[i] = (c & 7) * 8;
  }
  const u16* kbase = kb + (long)b * S * 384 + hoff;
  const u16* vbase = vt + (long)bh * 256 * S;

  // Q fragments (B-operand role)
  const long qrowb = ((long)b * S + q0 + lr) * 384 + hoff + g * 8;
  short8 qf[6];
#pragma unroll
  for (int ks = 0; ks < 6; ks++) qf[ks] = *(const short8*)&qb[qrowb + ks * 32];

  f32x4 accO[12];
  const f32x4 zero4 = {0.f, 0.f, 0.f, 0.f};
#pragma unroll
  for (int j = 0; j < 12; j++) accO[j] = zero4;
  float m = -1e30f, lsum = 0.f;

  // prologue: load tile 0 into regs
  short8 kst[3], vst[3];
#pragma unroll
  for (int i = 0; i < 3; i++) {
    kst[i] = *(const short8*)&kbase[(long)(kbeg + kr[i]) * 384 + kc[i]];
    vst[i] = *(const short8*)&vbase[(long)vr[i] * S + kbeg + vc[i]];
  }

  for (int kt = kbeg; kt < kbeg + KS; kt += 64) {
    __syncthreads();
#pragma unroll
    for (int i = 0; i < 3; i++) {
      *(short8*)&Ks[KSW(kr[i], kc[i])] = kst[i];
      *(short8*)&Vs[vr[i] * VSTR + vc[i]] = vst[i];
    }
    __syncthreads();
    if (kt + 64 < kbeg + KS) {
#pragma unroll
      for (int i = 0; i < 3; i++) {
        kst[i] = *(const short8*)&kbase[(long)(kt + 64 + kr[i]) * 384 + kc[i]];
        vst[i] = *(const short8*)&vbase[(long)vr[i] * S + kt + 64 + vc[i]];
      }
    }
    // ---- QK^T swapped: 4 independent chains (one per key-frag) ----
    f32x4 sacc[4];
#pragma unroll
    for (int f = 0; f < 4; f++) sacc[f] = zero4;
    __builtin_amdgcn_s_setprio(1);
#pragma unroll
    for (int ks = 0; ks < 6; ks++) {
#pragma unroll
      for (int f = 0; f < 4; f++) {
        short8 kf = *(const short8*)&Ks[KSW(f * 16 + lr, ks * 32 + g * 8)];
        sacc[f] = __builtin_amdgcn_mfma_f32_16x16x32_bf16(kf, qf[ks], sacc[f], 0, 0, 0);
      }
    }
    __builtin_amdgcn_s_setprio(0);
    // ---- scale + additive mask ----
#pragma unroll
    for (int f = 0; f < 4; f++) {
      if (maska) {
        float4 mk4 = *(const float4*)&maska[(long)b * S + kt + f * 16 + 4 * g];
        sacc[f][0] = fmaf(sacc[f][0], scale, mk4.x);
        sacc[f][1] = fmaf(sacc[f][1], scale, mk4.y);
        sacc[f][2] = fmaf(sacc[f][2], scale, mk4.z);
        sacc[f][3] = fmaf(sacc[f][3], scale, mk4.w);
      } else {
#pragma unroll
        for (int r = 0; r < 4; r++) sacc[f][r] *= scale;
      }
    }
    // ---- online softmax with defer-max (THR=8) ----
    float tm = sacc[0][0];
#pragma unroll
    for (int f = 0; f < 4; f++)
#pragma unroll
      for (int r = 0; r < 4; r++) tm = fmaxf(tm, sacc[f][r]);
    tm = fmaxf(tm, __shfl_xor(tm, 16));
    tm = fmaxf(tm, __shfl_xor(tm, 32));
    if (__any(tm > m + 8.f)) {
      float mn = fmaxf(m, tm);
      float al = __expf(m - mn);
      m = mn;
      lsum *= al;
#pragma unroll
      for (int j = 0; j < 12; j++)
#pragma unroll
        for (int r = 0; r < 4; r++) accO[j][r] *= al;
    }
    float rs = 0.f;
#pragma unroll
    for (int f = 0; f < 4; f++)
#pragma unroll
      for (int r = 0; r < 4; r++) {
        float p = __expf(sacc[f][r] - m);
        sacc[f][r] = p;
        rs += p;
      }
    rs += __shfl_xor(rs, 16);
    rs += __shfl_xor(rs, 32);
    lsum += rs;
    // ---- P^T -> per-wave LDS via cvt_pk + b64 stores ----
#pragma unroll
    for (int f = 0; f < 4; f++) {
      uint2 pp;
      pp.x = cvtpk(sacc[f][0], sacc[f][1]);
      pp.y = cvtpk(sacc[f][2], sacc[f][3]);
      *(uint2*)&PsT[w][lr * PSTR + f * 16 + 4 * g] = pp;
    }
    // ---- PV: 2 x K=32 steps over the 64 keys ----
    __builtin_amdgcn_s_setprio(1);
#pragma unroll
    for (int ks = 0; ks < 2; ks++) {
      short8 pT = *(const short8*)&PsT[w][lr * PSTR + ks * 32 + g * 8];
#pragma unroll
      for (int j = 0; j < 12; j++) {
        short8 vf = *(const short8*)&Vs[(j * 16 + lr) * VSTR + ks * 32 + g * 8];
        accO[j] = __builtin_amdgcn_mfma_f32_16x16x32_bf16(vf, pT, accO[j], 0, 0, 0);
      }
    }
    __builtin_amdgcn_s_setprio(0);
  }
  // ---- epilogue: unnormalized partials + (m, l) ----
  const long orow = ((long)(z * 32 + bh) * S + q0 + lr) * 192;
#pragma unroll
  for (int j = 0; j < 12; j++) {
    uint2 oo;
    oo.x = cvtpk(accO[j][0], accO[j][1]);
    oo.y = cvtpk(accO[j][2], accO[j][3]);
    *(uint2*)&opart[orow + j * 16 + 4 * g] = oo;
  }
  if (g == 0) {
    long mi = ((long)(z * 32 + bh) * S + q0 + lr) * 2;
    mlpart[mi] = m;
    mlpart[mi + 1] = lsum;
  }
}

// ================= merge split-K attention partials ==========================
__global__ __launch_bounds__(256) void fmerge(const u16* __restrict__ opart,
                                              const float* __restrict__ mlpart,
                                              u16* __restrict__ ob, int S) {
  long cid = (long)blockIdx.x * 256 + threadIdx.x;
  long nch = (long)32 * S * 24;
  if (cid >= nch) return;
  int row = (int)(cid / 24);
  int c8 = (int)(cid % 24) * 8;
  int bh = row / S, q = row - bh * S;
  int b = bh >> 1, h = bh & 1;
  long zs = (long)32 * S;
  float m0 = mlpart[(long)row * 2], l0 = mlpart[(long)row * 2 + 1];
  float m1 = mlpart[(zs + row) * 2], l1 = mlpart[(zs + row) * 2 + 1];
  float M = fmaxf(m0, m1);
  float a0 = __expf(m0 - M), a1 = __expf(m1 - M);
  float invL = 1.f / (a0 * l0 + a1 * l1);
  a0 *= invL; a1 *= invL;
  short8 o0 = *(const short8*)&opart[(long)row * 192 + c8];
  short8 o1 = *(const short8*)&opart[zs * 192 + (long)row * 192 + c8];
  float v[8];
#pragma unroll
  for (int j = 0; j < 8; j++)
    v[j] = a0 * b2f((u16)o0[j]) + a1 * b2f((u16)o1[j]);
  uint4 oo;
  oo.x = cvtpk(v[0], v[1]);
  oo.y = cvtpk(v[2], v[3]);
  oo.z = cvtpk(v[4], v[5]);
  oo.w = cvtpk(v[6], v[7]);
  *(uint4*)&ob[((long)b * S + q) * 384 + h * 192 + c8] = oo;
}

// ============== weight convert+transpose: [K,N] f32 -> [N,K] bf16 ============
__global__ void wconv_t(const float* __restrict__ src, u16* __restrict__ dst, int K, int N) {
  __shared__ float t[32][33];
  long mb = blockIdx.z;
  src += mb * (long)K * N;
  dst += mb * (long)K * N;
  int n0 = blockIdx.x * 32, k0 = blockIdx.y * 32;
  int tx = threadIdx.x, ty = threadIdx.y;
#pragma unroll
  for (int i = 0; i < 4; i++) {
    int r = ty + i * 8;
    t[r][tx] = src[(long)(k0 + r) * N + n0 + tx];
  }
  __syncthreads();
#pragma unroll
  for (int i = 0; i < 4; i++) {
    int r = ty + i * 8;
    dst[(long)(n0 + r) * K + k0 + tx] = f2b(t[tx][r]);
  }
}

// ============== mel weight: [384][80] f32 -> [128 (pad0)][384] bf16 ==========
__global__ void melw_t(const float* __restrict__ src, u16* __restrict__ dst) {
  int i = blockIdx.x * 256 + threadIdx.x;
  if (i >= 128 * 384) return;
  int n = i / 384, kk2 = i - n * 384;
  dst[i] = (n < NMELB) ? f2b(src[(long)kk2 * NMELB + n]) : (u16)0;
}

// ============================ positional encoding ============================
__global__ void posenc_kernel(float* __restrict__ pe) {
  int i = blockIdx.x * 256 + threadIdx.x;
  if (i >= TFR * DMODEL) return;
  int t = i / DMODEL, d = i - t * DMODEL;
  float f = (2.0f * (float)(d >> 1)) / (float)DMODEL;
  float ang = (float)t * powf(10000.0f, -f);
  pe[i] = (d & 1) ? cosf(ang) : sinf(ang);
}

// ===================== embedding + scaled PE (bf16 x) ========================
__global__ void embed_kernel(const int* __restrict__ ph, const float* __restrict__ emb,
                             const float* __restrict__ pe, const float* __restrict__ alpha,
                             u16* __restrict__ xb) {
  int i = blockIdx.x * 256 + threadIdx.x;
  if (i >= BATCH * LPH * DMODEL) return;
  int d = i % DMODEL;
  int bl = i / DMODEL;
  int l = bl % LPH;
  float v = emb[ph[bl] * DMODEL + d] + alpha[0] * pe[l * DMODEL + d];
  xb[i] = f2b(v);
}

// ====== LayerNorm, vectorized: wave-per-row, C/8 active lanes x 8 elems ======
// f32 in-place (duration-predictor path).
template <int C>
__global__ __launch_bounds__(256) void lnw(float* __restrict__ x, const float* __restrict__ gamma,
                                           const float* __restrict__ beta,
                                           float* __restrict__ outf, u16* __restrict__ outb) {
  const int w = threadIdx.x >> 6, l = threadIdx.x & 63;
  const long row = (long)blockIdx.x * 4 + w;
  constexpr int NL = C / 8;
  float* xr = x + row * C;
  float v[8];
  float s1 = 0.f, s2 = 0.f;
  if (l < NL) {
    float4 a = *(const float4*)&xr[8 * l];
    float4 bq = *(const float4*)&xr[8 * l + 4];
    v[0] = a.x; v[1] = a.y; v[2] = a.z; v[3] = a.w;
    v[4] = bq.x; v[5] = bq.y; v[6] = bq.z; v[7] = bq.w;
#pragma unroll
    for (int j = 0; j < 8; j++) { s1 += v[j]; s2 += v[j] * v[j]; }
  }
#pragma unroll
  for (int off = 1; off < 64; off <<= 1) {
    s1 += __shfl_xor(s1, off);
    s2 += __shfl_xor(s2, off);
  }
  float mean = s1 / C;
  float var = s2 / C - mean * mean;
  float rstd = rsqrtf(var + 1e-6f);
  if (l < NL) {
    float4 g0 = *(const float4*)&gamma[8 * l];
    float4 g1 = *(const float4*)&gamma[8 * l + 4];
    float4 b0 = *(const float4*)&beta[8 * l];
    float4 b1 = *(const float4*)&beta[8 * l + 4];
    float o[8];
    o[0] = (v[0] - mean) * rstd * g0.x + b0.x;
    o[1] = (v[1] - mean) * rstd * g0.y + b0.y;
    o[2] = (v[2] - mean) * rstd * g0.z + b0.z;
    o[3] = (v[3] - mean) * rstd * g0.w + b0.w;
    o[4] = (v[4] - mean) * rstd * g1.x + b1.x;
    o[5] = (v[5] - mean) * rstd * g1.y + b1.y;
    o[6] = (v[6] - mean) * rstd * g1.z + b1.z;
    o[7] = (v[7] - mean) * rstd * g1.w + b1.w;
    float* tf = outf ? outf + row * C : xr;
    *(float4*)&tf[8 * l] = make_float4(o[0], o[1], o[2], o[3]);
    *(float4*)&tf[8 * l + 4] = make_float4(o[4], o[5], o[6], o[7]);
    if (outb) {
      uint4 ob4;
      ob4.x = cvtpk(o[0], o[1]);
      ob4.y = cvtpk(o[2], o[3]);
      ob4.z = cvtpk(o[4], o[5]);
      ob4.w = cvtpk(o[6], o[7]);
      *(uint4*)&outb[row * C + 8 * l] = ob4;
    }
  }
}

// ====== LayerNorm over split-K partials + bias + bf16 residual (vectorized) ==
// x = LN(b2f(p0)+b2f(p1)+bias+b2f(resb)). outb may alias resb (per-thread
// read-before-write). outf optional f32 copy (encoder final -> Henc).
template <int C>
__global__ __launch_bounds__(256) void lnsum(const u16* __restrict__ p0, const u16* __restrict__ p1,
                                             const float* __restrict__ bias,
                                             const u16* __restrict__ resb,
                                             const float* __restrict__ gamma,
                                             const float* __restrict__ beta,
                                             float* __restrict__ outf, u16* __restrict__ outb) {
  const int w = threadIdx.x >> 6, l = threadIdx.x & 63;
  const long row = (long)blockIdx.x * 4 + w;
  constexpr int NL = C / 8;
  float v[8];
  float s1 = 0.f, s2 = 0.f;
  if (l < NL) {
    short8 a = *(const short8*)&p0[row * C + 8 * l];
    short8 bq = *(const short8*)&p1[row * C + 8 * l];
    short8 r = *(const short8*)&resb[row * C + 8 * l];
    float4 bi0 = *(const float4*)&bias[8 * l];
    float4 bi1 = *(const float4*)&bias[8 * l + 4];
#pragma unroll
    for (int j = 0; j < 8; j++) {
      float bb = (j < 4) ? (&bi0.x)[j] : (&bi1.x)[j - 4];
      v[j] = b2f((u16)a[j]) + b2f((u16)bq[j]) + bb + b2f((u16)r[j]);
      s1 += v[j];
      s2 += v[j] * v[j];
    }
  }
#pragma unroll
  for (int off = 1; off < 64; off <<= 1) {
    s1 += __shfl_xor(s1, off);
    s2 += __shfl_xor(s2, off);
  }
  float mean = s1 / C;
  float var = s2 / C - mean * mean;
  float rstd = rsqrtf(var + 1e-6f);
  if (l < NL) {
    float4 g0 = *(const float4*)&gamma[8 * l];
    float4 g1 = *(const float4*)&gamma[8 * l + 4];
    float4 b0 = *(const float4*)&beta[8 * l];
    float4 b1 = *(const float4*)&beta[8 * l + 4];
    float o[8];
    o[0] = (v[0] - mean) * rstd * g0.x + b0.x;
    o[1] = (v[1] - mean) * rstd * g0.y + b0.y;
    o[2] = (v[2] - mean) * rstd * g0.z + b0.z;
    o[3] = (v[3] - mean) * rstd * g0.w + b0.w;
    o[4] = (v[4] - mean) * rstd * g1.x + b1.x;
    o[5] = (v[5] - mean) * rstd * g1.y + b1.y;
    o[6] = (v[6] - mean) * rstd * g1.z + b1.z;
    o[7] = (v[7] - mean) * rstd * g1.w + b1.w;
    if (outf) {
      *(float4*)&outf[row * C + 8 * l] = make_float4(o[0], o[1], o[2], o[3]);
      *(float4*)&outf[row * C + 8 * l + 4] = make_float4(o[4], o[5], o[6], o[7]);
    }
    if (outb) {
      uint4 ob4;
      ob4.x = cvtpk(o[0], o[1]);
      ob4.y = cvtpk(o[2], o[3]);
      ob4.z = cvtpk(o[4], o[5]);
      ob4.w = cvtpk(o[6], o[7]);
      *(uint4*)&outb[row * C + 8 * l] = ob4;
    }
  }
}

// ==================== im2col for K=3 SAME conv (f32 -> bf16) =================
template <int CIN>
__global__ __launch_bounds__(256) void im2col3(const float* __restrict__ x,
                                               u16* __restrict__ a) {
  const int PER = (3 * CIN) / 8;
  long idx = (long)blockIdx.x * 256 + threadIdx.x;
  if (idx >= (long)BATCH * LPH * PER) return;
  int row = (int)(idx / PER);
  int e8 = (int)(idx - (long)row * PER) * 8;
  int kk = e8 / CIN, ci = e8 - kk * CIN;
  int b = row >> 7, l = row & (LPH - 1);
  int gl = l + kk - 1;
  ushort4 o0 = {0, 0, 0, 0}, o1 = {0, 0, 0, 0};
  if (gl >= 0 && gl < LPH) {
    const float* src = x + ((long)(b * LPH + gl) * CIN + ci);
    float4 v0 = *(const float4*)src;
    float4 v1 = *(const float4*)(src + 4);
    o0.x = f2b(v0.x); o0.y = f2b(v0.y); o0.z = f2b(v0.z); o0.w = f2b(v0.w);
    o1.x = f2b(v1.x); o1.y = f2b(v1.y); o1.z = f2b(v1.z); o1.w = f2b(v1.w);
  }
  *(ushort4*)&a[(long)row * (3 * CIN) + e8] = o0;
  *(ushort4*)&a[(long)row * (3 * CIN) + e8 + 4] = o1;
}

// ============================ duration projection ============================
__global__ void dpout_kernel(const float* __restrict__ d2, const float* __restrict__ w,
                             const float* __restrict__ bb, float* __restrict__ out) {
  int wv = threadIdx.x >> 6, lane = threadIdx.x & 63;
  int row = blockIdx.x * 4 + wv;
  const float* xr = d2 + (long)row * CDPC;
  float s = 0.f;
  for (int c = lane; c < CDPC; c += 64) s = fmaf(xr[c], w[c], s);
#pragma unroll
  for (int off = 32; off > 0; off >>= 1) s += __shfl_down(s, off);
  if (lane == 0) out[row] = s + bb[0];
}

// ============================ length regulator ===============================
__global__ void regulator_kernel(const int* __restrict__ durations, int* __restrict__ idx,
                                 float* __restrict__ maskv, float* __restrict__ maska) {
  __shared__ int cum[LPH];
  __shared__ int total;
  int b = blockIdx.x;
  if (threadIdx.x == 0) {
    int s = 0;
    for (int j = 0; j < LPH; j++) { s += durations[b * LPH + j]; cum[j] = s; }
    total = s;
  }
  __syncthreads();
  for (int t = threadIdx.x; t < TFR; t += blockDim.x) {
    int cnt = 0;
    for (int j = 0; j < LPH; j++) cnt += (cum[j] <= t) ? 1 : 0;
    if (cnt > LPH - 1) cnt = LPH - 1;
    idx[b * TFR + t] = cnt;
    maskv[b * TFR + t] = (t < total) ? 0.f : 1.f;   // 1 = masked (multiplicative)
    maska[b * TFR + t] = (t < total) ? 0.f : NEGV;  // additive logit bias
  }
}

// gather expanded states, apply valid mask, add scaled PE (bf16 out)
__global__ void gather_kernel(const float* __restrict__ h, const int* __restrict__ idx,
                              const float* __restrict__ maskv, const float* __restrict__ pe,
                              const float* __restrict__ alpha, u16* __restrict__ yb) {
  long i = (long)blockIdx.x * 256 + threadIdx.x;
  if (i >= (long)BATCH * TFR * DMODEL) return;
  int d = (int)(i % DMODEL);
  long bt = i / DMODEL;
  int t = (int)(bt % TFR);
  long b = bt / TFR;
  float valid = 1.0f - maskv[bt];
  float v = h[((long)b * LPH + idx[bt]) * DMODEL + d] * valid + alpha[0] * pe[t * DMODEL + d];
  yb[i] = f2b(v);
}

// ============================ launcher =======================================
extern "C" void kernel_launch(void* const* d_in, const int* in_sizes, int n_in,
                              void* d_out, int out_size, void* d_ws, size_t ws_size,
                              hipStream_t stream) {
  const int* phonemes = (const int*)d_in[0];
  const int* durations = (const int*)d_in[1];
  const float* embedw = (const float*)d_in[2];
  const float* alpha_enc = (const float*)d_in[3];
  const float* alpha_dec = (const float*)d_in[4];
  const float* enc_attn_w = (const float*)d_in[5];
  const float* enc_attn_b = (const float*)d_in[6];
  const float* enc_ffn_w1 = (const float*)d_in[7];
  const float* enc_ffn_b1 = (const float*)d_in[8];
  const float* enc_ffn_w2 = (const float*)d_in[9];
  const float* enc_ffn_b2 = (const float*)d_in[10];
  const float* enc_ln = (const float*)d_in[11];
  const float* dec_attn_w = (const float*)d_in[12];
  const float* dec_attn_b = (const float*)d_in[13];
  const float* dec_ffn_w1 = (const float*)d_in[14];
  const float* dec_ffn_b1 = (const float*)d_in[15];
  const float* dec_ffn_w2 = (const float*)d_in[16];
  const float* dec_ffn_b2 = (const float*)d_in[17];
  const float* dec_ln = (const float*)d_in[18];
  const float* dp_conv1_w = (const float*)d_in[19];
  const float* dp_conv1_b = (const float*)d_in[20];
  const float* dp_conv2_w = (const float*)d_in[21];
  const float* dp_conv2_b = (const float*)d_in[22];
  const float* dp_ln = (const float*)d_in[23];
  const float* dp_out_w = (const float*)d_in[24];
  const float* dp_out_b = (const float*)d_in[25];
  const float* mel_w = (const float*)d_in[26];
  const float* mel_b = (const float*)d_in[27];

  // ---- workspace map (bytes). Post-LN: residual carrier == Xb (bf16). ----
  char* base = (char*)d_ws;
  u16* FP = (u16*)base;                        // 25,165,824  FFN2 split-K partials
  u16* Xb = (u16*)(base + 25165824);           // 12,582,912  bf16 x (LN out = residual)
  u16* QKb = (u16*)(base + 37748736);          // 25,165,824  q, k (AOb/Mb overlay)
  char* E = base + 62914560;                   // 33,554,432  attn/AO partials, DP scratch
  u16* Vt = (u16*)(base + 96468992);           // 16,777,216  V^T [32][256][S]
  u16* Wb = (u16*)(base + 113246208);          // 21,233,664  bf16 weights (per stack)
  float* Henc = (float*)(base + 134479872);    // 3,145,728   encoder output h (f32)
  float* PE = (float*)(base + 137625600);      // 1,572,864
  float* MASKD = (float*)(base + 139198464);   // 65,536
  int* IDX = (int*)(base + 139264000);         // 65,536
  u16* Wmel = (u16*)(base + 139329536);        // 98,304      [128][384] bf16
  float* MASKA = (float*)(base + 139427840);   // 65,536      additive mask

  u16* AOb = QKb;
  u16* Mb = QKb;  // FFN mid overlays q/k/attn-out (dead by then)

  // attention split-K partials + AO partials in E (phase-disjoint)
  u16* OPART = (u16*)E;
  float* MLPART = (float*)(E + 25165824);
  u16* AOP = (u16*)E;

  // duration-predictor overlays in E
  float* DP1 = (float*)E;
  float* DP2 = DP1 + (size_t)2048 * CDPC;
  u16* A1 = (u16*)(E + 4 * 1024 * 1024);
  u16* A2 = (u16*)(E + 9 * 1024 * 1024);
  u16* Wdp1 = (u16*)(E + 13 * 1024 * 1024);
  u16* Wdp2 = (u16*)(E + 15 * 1024 * 1024);

  u16* WAt = Wb;                 // 24 x [384][384]
  u16* W1t = Wb + 3538944;       // 6 x [1536][384]
  u16* W2t = Wb + 7077888;       // 6 x [384][1536]

  const int Me = BATCH * LPH;    // 2048
  const int Md = BATCH * TFR;    // 16384
  const long DD = 384L * 384;
  const long NXe = (long)Me * DMODEL;   // 786,432
  const long NXd = (long)Md * DMODEL;   // 6,291,456
  dim3 tb32(32, 8);

  posenc_kernel<<<(TFR * DMODEL + 255) / 256, 256, 0, stream>>>(PE);
  embed_kernel<<<(Me * DMODEL + 255) / 256, 256, 0, stream>>>(phonemes, embedw, PE, alpha_enc, Xb);
  wconv_t<<<dim3(12, 12, 24), tb32, 0, stream>>>(enc_attn_w, WAt, 384, 384);
  wconv_t<<<dim3(48, 12, 6), tb32, 0, stream>>>(enc_ffn_w1, W1t, 384, 1536);
  wconv_t<<<dim3(12, 48, 6), tb32, 0, stream>>>(enc_ffn_w2, W2t, 1536, 384);
  melw_t<<<192, 256, 0, stream>>>(mel_w, Wmel);

  // -------- phoneme encoder (x stream in Xb only) --------
  for (int i = 0; i < NLAYER; i++) {
    const u16* wa = WAt + (size_t)i * 4 * DD;
    const float* ab = enc_attn_b + (size_t)i * 4 * 384;
    bgemm<(FBIAS | FOB16 | FVT)><<<dim3(3, 16, 3), 256, 0, stream>>>(
        Xb, wa, ab, nullptr, QKb, Vt, 384, 384, 384, 384, 384,
        1, 0, 0, DD, 0, NXe, 0, 128);
    fattn<<<dim3(1, 32, 2), 512, 0, stream>>>(QKb, QKb + NXe, Vt, nullptr, OPART, MLPART, 128, 0);
    fmerge<<<384, 256, 0, stream>>>(OPART, MLPART, AOb, 128);
    bgemm<(FOB16)><<<dim3(3, 16, 2), 256, 0, stream>>>(
        AOb, wa + 3 * DD, nullptr, nullptr, AOP, nullptr, 384, 192, 384, 384, 384,
        2, 0, 192, 0, 192, 0, NXe, 0);
    lnsum<384><<<Me / 4, 256, 0, stream>>>(AOP, AOP + NXe, ab + 3 * 384, Xb,
                                           enc_ln + ((size_t)(i * 2 + 0) * 2 + 0) * 384,
                                           enc_ln + ((size_t)(i * 2 + 0) * 2 + 1) * 384,
                                           nullptr, Xb);
    bgemm<(FBIAS | FRELU | FOB16)><<<dim3(12, 16, 1), 256, 0, stream>>>(
        Xb, W1t + (size_t)i * 589824, enc_ffn_b1 + (size_t)i * 1536, nullptr, Mb, nullptr,
        1536, 384, 384, 384, 1536, 1, 0, 0, 0, 0, 0, 0, 0);
    bgemm<(FOB16)><<<dim3(3, 16, 2), 256, 0, stream>>>(
        Mb, W2t + (size_t)i * 589824, nullptr, nullptr, FP, nullptr,
        384, 768, 1536, 1536, 384, 2, 0, 768, 0, 768, 0, NXe, 0);
    lnsum<384><<<Me / 4, 256, 0, stream>>>(FP, FP + NXe, enc_ffn_b2 + (size_t)i * 384, Xb,
                                           enc_ln + ((size_t)(i * 2 + 1) * 2 + 0) * 384,
                                           enc_ln + ((size_t)(i * 2 + 1) * 2 + 1) * 384,
                                           (i == NLAYER - 1) ? Henc : nullptr, Xb);
  }

  // -------- duration predictor (h = Henc) via im2col + bf16 GEMM --------
  wconv_t<<<dim3(8, 36, 1), tb32, 0, stream>>>(dp_conv1_w, Wdp1, 1152, 256);
  wconv_t<<<dim3(8, 24, 1), tb32, 0, stream>>>(dp_conv2_w, Wdp2, 768, 256);
  im2col3<DMODEL><<<(Me * 144 + 255) / 256, 256, 0, stream>>>(Henc, A1);
  bgemm<(FBIAS | FRELU)><<<dim3(2, 16, 1), 256, 0, stream>>>(
      A1, Wdp1, dp_conv1_b, nullptr, DP1, nullptr, 256, 1152, 1152, 1152, 256,
      1, 0, 0, 0, 0, 0, 0, 0);
  lnw<256><<<Me / 4, 256, 0, stream>>>(DP1, dp_ln + 0 * CDPC, dp_ln + 1 * CDPC, nullptr, nullptr);
  im2col3<CDPC><<<(Me * 96 + 255) / 256, 256, 0, stream>>>(DP1, A2);
  bgemm<(FBIAS | FRELU)><<<dim3(2, 16, 1), 256, 0, stream>>>(
      A2, Wdp2, dp_conv2_b, nullptr, DP2, nullptr, 256, 768, 768, 768, 256,
      1, 0, 0, 0, 0, 0, 0, 0);
  lnw<256><<<Me / 4, 256, 0, stream>>>(DP2, dp_ln + 2 * CDPC, dp_ln + 3 * CDPC, nullptr, nullptr);
  float* durout = (float*)d_out + (size_t)Md * NMELB;
  dpout_kernel<<<Me / 4, 256, 0, stream>>>(DP2, dp_out_w, dp_out_b, durout);

  // -------- length regulator --------
  regulator_kernel<<<BATCH, 256, 0, stream>>>(durations, IDX, MASKD, MASKA);
  gather_kernel<<<(int)((NXd + 255) / 256), 256, 0, stream>>>(Henc, IDX, MASKD, PE, alpha_dec, Xb);
  wconv_t<<<dim3(12, 12, 24), tb32, 0, stream>>>(dec_attn_w, WAt, 384, 384);
  wconv_t<<<dim3(48, 12, 6), tb32, 0, stream>>>(dec_ffn_w1, W1t, 384, 1536);
  wconv_t<<<dim3(12, 48, 6), tb32, 0, stream>>>(dec_ffn_w2, W2t, 1536, 384);

  // -------- mel decoder --------
  for (int i = 0; i < NLAYER; i++) {
    const u16* wa = WAt + (size_t)i * 4 * DD;
    const float* ab = dec_attn_b + (size_t)i * 4 * 384;
    bgemm<(FBIAS | FOB16 | FVT)><<<dim3(3, 128, 3), 256, 0, stream>>>(
        Xb, wa, ab, nullptr, QKb, Vt, 384, 384, 384, 384, 384,
        1, 0, 0, DD, 0, NXd, 0, 1024);
    fattn<<<dim3(8, 32, 2), 512, 0, stream>>>(QKb, QKb + NXd, Vt, MASKA, OPART, MLPART, 1024, 3);
    fmerge<<<3072, 256, 0, stream>>>(OPART, MLPART, AOb, 1024);
    bgemm<(FOB16)><<<dim3(3, 128, 2), 256, 0, stream>>>(
        AOb, wa + 3 * DD, nullptr, nullptr, AOP, nullptr, 384, 192, 384, 384, 384,
        2, 0, 192, 0, 192, 0, NXd, 0);
    lnsum<384><<<Md / 4, 256, 0, stream>>>(AOP, AOP + NXd, ab + 3 * 384, Xb,
                                           dec_ln + ((size_t)(i * 2 + 0) * 2 + 0) * 384,
                                           dec_ln + ((size_t)(i * 2 + 0) * 2 + 1) * 384,
                                           nullptr, Xb);
    bgemm<(FBIAS | FRELU | FOB16)><<<dim3(12, 128, 1), 256, 0, stream>>>(
        Xb, W1t + (size_t)i * 589824, dec_ffn_b1 + (size_t)i * 1536, nullptr, Mb, nullptr,
        1536, 384, 384, 384, 1536, 1, 0, 0, 0, 0, 0, 0, 0);
    bgemm<(FOB16)><<<dim3(3, 128, 2), 256, 0, stream>>>(
        Mb, W2t + (size_t)i * 589824, nullptr, nullptr, FP, nullptr,
        384, 768, 1536, 1536, 384, 2, 0, 768, 0, 768, 0, NXd, 0);
    lnsum<384><<<Md / 4, 256, 0, stream>>>(FP, FP + NXd, dec_ffn_b2 + (size_t)i * 384, Xb,
                                           dec_ln + ((size_t)(i * 2 + 1) * 2 + 0) * 384,
                                           dec_ln + ((size_t)(i * 2 + 1) * 2 + 1) * 384,
                                           nullptr, Xb);
  }

  // -------- mel projection (bf16 MFMA, N=80 padded to 128) --------
  bgemm<(FBIAS)><<<dim3(1, 128, 1), 256, 0, stream>>>(
      Xb, Wmel, mel_b, nullptr, (float*)d_out, nullptr, 80, 384, 384, 384, 80,
      1, 0, 0, 0, 0, 0, 0, 0);
}

// Round 21
// 1669.820 us; speedup vs baseline: 1.0039x; 1.0039x over previous
//
#include <hip/hip_runtime.h>
#include <math.h>

#define BATCH 16
#define LPH 128
#define TFR 1024
#define DMODEL 384
#define FDIM 1536
#define NLAYER 6
#define NMELB 80
#define CDPC 256
#define NEGV (-1e9f)

typedef unsigned short u16;
typedef __attribute__((ext_vector_type(8))) short short8;
typedef __attribute__((ext_vector_type(4))) float f32x4;

__device__ __forceinline__ float b2f(u16 u) {
  return __uint_as_float(((unsigned)u) << 16);
}
__device__ __forceinline__ u16 f2b(float f) {
  unsigned x = __float_as_uint(f);
  return (u16)((x + 0x7fffu + ((x >> 16) & 1u)) >> 16);
}
// pack 2 f32 -> 2 bf16 in one HW op (no builtin on gfx950; inline asm per T12)
__device__ __forceinline__ unsigned cvtpk(float lo, float hi) {
  unsigned r;
  asm volatile("v_cvt_pk_bf16_f32 %0, %1, %2" : "=v"(r) : "v"(lo), "v"(hi));
  return r;
}

#define GLOAD16(gp, lp)                                                                   \
  __builtin_amdgcn_global_load_lds((const __attribute__((address_space(1))) void*)(gp),   \
                                   (__attribute__((address_space(3))) void*)(lp), 16, 0, 0)

#define FBIAS 1
#define FRES 2
#define FRELU 4
#define FOB16 8
#define FVT 16

// ===================== bf16 MFMA GEMM, 128x128 tile, BK=64 ===================
// C[M,N] = act(A[M,K] @ Bt[N,K]^T + bias (+res)). A,Bt bf16 row-major (k-contig).
// LDS tiles [128][64] with XOR swizzle (rule #21: linear gload_lds dest +
// pre-swizzled GLOBAL column + swizzled ds_read) -> 2-way bank alias (free).
// BK=64 halves barrier drains. K % 64 == 0. (R19-proven: explicit 2-phase
// dbuf was NEUTRAL vs this — R20 A/B; implicit wave overlap already covers it.)
// XCD-aware tile remap; split-K via z (partials, bias folded into lnsum).
// FVT: for z==2 (V of QKV), LDS-transposed coalesced Vt store; Ts overlays As/Bs.
#define GSW(r, c) ((r) * 64 + ((c) ^ (((r)&7) << 3)))
template <int FL>
__global__ __launch_bounds__(256) void bgemm(
    const u16* __restrict__ A, const u16* __restrict__ Bt,
    const float* __restrict__ bias, const float* __restrict__ res,
    void* __restrict__ Cv, u16* __restrict__ VtP,
    int N, int K, int lda, int ldb, int ldc,
    int zdiv, long az0, long az1, long bz0, long bz1, long cz0, long cz1, int S) {
  constexpr int SMEMSZ = (FL & FVT) ? (128 * 136) : 16384;
  __shared__ __align__(16) u16 smem[SMEMSZ];
  u16* As = smem;
  u16* Bs = smem + 8192;
  const int tid = threadIdx.x;
  const int wave = tid >> 6, lane = tid & 63;
  const int wm = wave >> 1, wn = wave & 1;
  const int lrow = lane & 15, lk = lane >> 4;
  const int z = blockIdx.z;
  const int zq = z / zdiv, zr = z - zq * zdiv;
  const long offA = (long)zq * az0 + (long)zr * az1;
  const long offB = (long)zq * bz0 + (long)zr * bz1;
  const long offC = (long)zq * cz0 + (long)zr * cz1;
  const int fid = blockIdx.x + gridDim.x * blockIdx.y;
  const int idx = fid >> 3;
  const int xl = idx % gridDim.x;
  const int yl = (fid & 7) + 8 * (idx / gridDim.x);
  const int row0 = yl * 128;
  const int col0 = xl * 128;

  const u16* gA[4];
  const u16* gB[4];
  u16* lA[4];
  u16* lB[4];
#pragma unroll
  for (int i = 0; i < 4; i++) {
    int c = tid + i * 256;
    int r = c >> 3, cg = c & 7;
    int swz = ((cg ^ (r & 7)) * 8);
    gA[i] = A + offA + (long)(row0 + r) * lda + swz;
    gB[i] = Bt + offB + (long)(col0 + r) * ldb + swz;
    lA[i] = As + c * 8;
    lB[i] = Bs + c * 8;
  }

  f32x4 acc[4][4];
  const f32x4 zero4 = {0.f, 0.f, 0.f, 0.f};
#pragma unroll
  for (int i = 0; i < 4; i++)
#pragma unroll
    for (int j = 0; j < 4; j++) acc[i][j] = zero4;

  for (int k0 = 0; k0 < K; k0 += 64) {
#pragma unroll
    for (int i = 0; i < 4; i++) {
      GLOAD16(gA[i], lA[i]);
      GLOAD16(gB[i], lB[i]);
    }
#pragma unroll
    for (int i = 0; i < 4; i++) { gA[i] += 64; gB[i] += 64; }
    __syncthreads();
#pragma unroll
    for (int kk = 0; kk < 2; kk++) {
      short8 av[4], bv[4];
#pragma unroll
      for (int mi = 0; mi < 4; mi++)
        av[mi] = *(const short8*)&As[GSW(wm * 64 + mi * 16 + lrow, kk * 32 + lk * 8)];
#pragma unroll
      for (int ni = 0; ni < 4; ni++)
        bv[ni] = *(const short8*)&Bs[GSW(wn * 64 + ni * 16 + lrow, kk * 32 + lk * 8)];
#pragma unroll
      for (int mi = 0; mi < 4; mi++)
#pragma unroll
        for (int ni = 0; ni < 4; ni++)
          acc[mi][ni] = __builtin_amdgcn_mfma_f32_16x16x32_bf16(av[mi], bv[ni], acc[mi][ni], 0, 0, 0);
    }
    __syncthreads();   // after this, As/Bs dead -> Ts overlay safe
  }

  const float* bz = (FL & FBIAS) ? bias + (long)z * N : nullptr;
  if constexpr ((FL & FVT) != 0) {
    if (z == 2) {
      u16* Ts = smem;
#pragma unroll
      for (int mi = 0; mi < 4; mi++) {
        int si = wm * 64 + lk * 4 + mi * 16;
#pragma unroll
        for (int ni = 0; ni < 4; ni++) {
          int cl = wn * 64 + ni * 16 + lrow;
          float bi = bz[col0 + cl];
          uint2 oo;
          oo.x = cvtpk(acc[mi][ni][0] + bi, acc[mi][ni][1] + bi);
          oo.y = cvtpk(acc[mi][ni][2] + bi, acc[mi][ni][3] + bi);
          *(uint2*)&Ts[cl * 136 + si] = oo;
        }
      }
      __syncthreads();
      const int ci = tid >> 1;
      const int cbase = (tid & 1) * 64;
      int c = col0 + ci;
      int hh = c / 192, dd = c - hh * 192;
      int bb = row0 / S;
      int ss = row0 % S;
      u16* dst = &VtP[((long)(bb * 2 + hh) * 256 + dd) * S + ss + cbase];
      const u16* srcr = &Ts[ci * 136 + cbase];
#pragma unroll
      for (int j = 0; j < 8; j++)
        *(short8*)&dst[j * 8] = *(const short8*)&srcr[j * 8];
      return;
    }
  }
  float* Cf = (float*)Cv + offC;
  u16* Cb = (u16*)Cv + offC;
  const float* resz = (FL & FRES) ? res + offC : nullptr;
#pragma unroll
  for (int mi = 0; mi < 4; mi++) {
    long rbase = row0 + wm * 64 + lk * 4 + (long)mi * 16;
#pragma unroll
    for (int ni = 0; ni < 4; ni++) {
      int c = col0 + wn * 64 + ni * 16 + lrow;
      if (c < N) {
        float bi = (FL & FBIAS) ? bz[c] : 0.f;
#pragma unroll
        for (int rr = 0; rr < 4; rr++) {
          float vv = acc[mi][ni][rr] + bi;
          if (FL & FRES) vv += resz[(rbase + rr) * (long)ldc + c];
          if (FL & FRELU) vv = fmaxf(vv, 0.f);
          if (FL & FOB16) Cb[(rbase + rr) * (long)ldc + c] = f2b(vv);
          else Cf[(rbase + rr) * (long)ldc + c] = vv;
        }
      }
    }
  }
}

// ============ fused flash attention, split-K partials (bf16 MFMA) ============
// 8 waves x 16 q-rows = 128 q-rows/block (512 thr); KVBLK=64.
// LDS 70.7 KB -> 2 blocks/CU (grid is 2/CU anyway). Natural VGPR (88, no spill).
// grid (QT, 32, 2). SWAPPED QK^T; defer-max; cvt_pk; additive mask.
#define KSW(r, c) ((r) * 192 + ((c) ^ (((r)&7) << 3)))
#define VSTR 72
#define PSTR 72
__global__ __launch_bounds__(512) void fattn(const u16* __restrict__ qb,
                                             const u16* __restrict__ kb,
                                             const u16* __restrict__ vt,
                                             const float* __restrict__ maska,  // 0 / -1e9
                                             u16* __restrict__ opart,
                                             float* __restrict__ mlpart,
                                             int S, int qtshift) {
  __shared__ __align__(16) u16 Ks[64 * 192];        // 24 KB (XOR swizzle)
  __shared__ __align__(16) u16 Vs[192 * VSTR];      // 27.6 KB (pad stride 144B)
  __shared__ __align__(16) u16 PsT[8][16 * PSTR];   // 18.4 KB per-wave P^T
  const int tid = threadIdx.x;
  const int w = tid >> 6, l = tid & 63;
  const int g = l >> 4, lr = l & 15;
  const int QT = gridDim.x;
  const int fid = (blockIdx.z * 32 + blockIdx.y) * QT + blockIdx.x;
  const int s = fid >> 3;
  const int gid = (fid & 7) * 8 + (s >> qtshift);  // 8 locality groups per XCD
  const int qt = s & (QT - 1);
  const int bh = gid & 31, z = gid >> 5;
  const int b = bh >> 1, h = bh & 1;
  const int q0 = qt * 128 + w * 16;
  const int hoff = h * 192;
  const int KS = S >> 1;
  const int kbeg = z * KS;
  const float scale = 0.0721687836f;  // 1/sqrt(192)

  // staging: K tile 64x192 = 1536 chunks, V tile 192x64 = 1536 chunks; 6/thread
  int kr[3], kc[3], vr[3], vc[3];
#pragma unroll
  for (int i = 0; i < 3; i++) {
    int c = tid + i * 512;
    kr[i] = c / 24; kc[i] = (c % 24) * 8;
    vr[i] = c >> 3; vc[i] = (c & 7) * 8;
  }
  const u16* kbase = kb + (long)b * S * 384 + hoff;
  const u16* vbase = vt + (long)bh * 256 * S;

  // Q fragments (B-operand role)
  const long qrowb = ((long)b * S + q0 + lr) * 384 + hoff + g * 8;
  short8 qf[6];
#pragma unroll
  for (int ks = 0; ks < 6; ks++) qf[ks] = *(const short8*)&qb[qrowb + ks * 32];

  f32x4 accO[12];
  const f32x4 zero4 = {0.f, 0.f, 0.f, 0.f};
#pragma unroll
  for (int j = 0; j < 12; j++) accO[j] = zero4;
  float m = -1e30f, lsum = 0.f;

  // prologue: load tile 0 into regs
  short8 kst[3], vst[3];
#pragma unroll
  for (int i = 0; i < 3; i++) {
    kst[i] = *(const short8*)&kbase[(long)(kbeg + kr[i]) * 384 + kc[i]];
    vst[i] = *(const short8*)&vbase[(long)vr[i] * S + kbeg + vc[i]];
  }

  for (int kt = kbeg; kt < kbeg + KS; kt += 64) {
    __syncthreads();
#pragma unroll
    for (int i = 0; i < 3; i++) {
      *(short8*)&Ks[KSW(kr[i], kc[i])] = kst[i];
      *(short8*)&Vs[vr[i] * VSTR + vc[i]] = vst[i];
    }
    __syncthreads();
    if (kt + 64 < kbeg + KS) {
#pragma unroll
      for (int i = 0; i < 3; i++) {
        kst[i] = *(const short8*)&kbase[(long)(kt + 64 + kr[i]) * 384 + kc[i]];
        vst[i] = *(const short8*)&vbase[(long)vr[i] * S + kt + 64 + vc[i]];
      }
    }
    // ---- QK^T swapped: 4 independent chains (one per key-frag) ----
    f32x4 sacc[4];
#pragma unroll
    for (int f = 0; f < 4; f++) sacc[f] = zero4;
    __builtin_amdgcn_s_setprio(1);
#pragma unroll
    for (int ks = 0; ks < 6; ks++) {
#pragma unroll
      for (int f = 0; f < 4; f++) {
        short8 kf = *(const short8*)&Ks[KSW(f * 16 + lr, ks * 32 + g * 8)];
        sacc[f] = __builtin_amdgcn_mfma_f32_16x16x32_bf16(kf, qf[ks], sacc[f], 0, 0, 0);
      }
    }
    __builtin_amdgcn_s_setprio(0);
    // ---- scale + additive mask ----
#pragma unroll
    for (int f = 0; f < 4; f++) {
      if (maska) {
        float4 mk4 = *(const float4*)&maska[(long)b * S + kt + f * 16 + 4 * g];
        sacc[f][0] = fmaf(sacc[f][0], scale, mk4.x);
        sacc[f][1] = fmaf(sacc[f][1], scale, mk4.y);
        sacc[f][2] = fmaf(sacc[f][2], scale, mk4.z);
        sacc[f][3] = fmaf(sacc[f][3], scale, mk4.w);
      } else {
#pragma unroll
        for (int r = 0; r < 4; r++) sacc[f][r] *= scale;
      }
    }
    // ---- online softmax with defer-max (THR=8) ----
    float tm = sacc[0][0];
#pragma unroll
    for (int f = 0; f < 4; f++)
#pragma unroll
      for (int r = 0; r < 4; r++) tm = fmaxf(tm, sacc[f][r]);
    tm = fmaxf(tm, __shfl_xor(tm, 16));
    tm = fmaxf(tm, __shfl_xor(tm, 32));
    if (__any(tm > m + 8.f)) {
      float mn = fmaxf(m, tm);
      float al = __expf(m - mn);
      m = mn;
      lsum *= al;
#pragma unroll
      for (int j = 0; j < 12; j++)
#pragma unroll
        for (int r = 0; r < 4; r++) accO[j][r] *= al;
    }
    float rs = 0.f;
#pragma unroll
    for (int f = 0; f < 4; f++)
#pragma unroll
      for (int r = 0; r < 4; r++) {
        float p = __expf(sacc[f][r] - m);
        sacc[f][r] = p;
        rs += p;
      }
    rs += __shfl_xor(rs, 16);
    rs += __shfl_xor(rs, 32);
    lsum += rs;
    // ---- P^T -> per-wave LDS via cvt_pk + b64 stores ----
#pragma unroll
    for (int f = 0; f < 4; f++) {
      uint2 pp;
      pp.x = cvtpk(sacc[f][0], sacc[f][1]);
      pp.y = cvtpk(sacc[f][2], sacc[f][3]);
      *(uint2*)&PsT[w][lr * PSTR + f * 16 + 4 * g] = pp;
    }
    // ---- PV: 2 x K=32 steps over the 64 keys ----
    __builtin_amdgcn_s_setprio(1);
#pragma unroll
    for (int ks = 0; ks < 2; ks++) {
      short8 pT = *(const short8*)&PsT[w][lr * PSTR + ks * 32 + g * 8];
#pragma unroll
      for (int j = 0; j < 12; j++) {
        short8 vf = *(const short8*)&Vs[(j * 16 + lr) * VSTR + ks * 32 + g * 8];
        accO[j] = __builtin_amdgcn_mfma_f32_16x16x32_bf16(vf, pT, accO[j], 0, 0, 0);
      }
    }
    __builtin_amdgcn_s_setprio(0);
  }
  // ---- epilogue: unnormalized partials + (m, l) ----
  const long orow = ((long)(z * 32 + bh) * S + q0 + lr) * 192;
#pragma unroll
  for (int j = 0; j < 12; j++) {
    uint2 oo;
    oo.x = cvtpk(accO[j][0], accO[j][1]);
    oo.y = cvtpk(accO[j][2], accO[j][3]);
    *(uint2*)&opart[orow + j * 16 + 4 * g] = oo;
  }
  if (g == 0) {
    long mi = ((long)(z * 32 + bh) * S + q0 + lr) * 2;
    mlpart[mi] = m;
    mlpart[mi + 1] = lsum;
  }
}

// ================= merge split-K attention partials ==========================
__global__ __launch_bounds__(256) void fmerge(const u16* __restrict__ opart,
                                              const float* __restrict__ mlpart,
                                              u16* __restrict__ ob, int S) {
  long cid = (long)blockIdx.x * 256 + threadIdx.x;
  long nch = (long)32 * S * 24;
  if (cid >= nch) return;
  int row = (int)(cid / 24);
  int c8 = (int)(cid % 24) * 8;
  int bh = row / S, q = row - bh * S;
  int b = bh >> 1, h = bh & 1;
  long zs = (long)32 * S;
  float m0 = mlpart[(long)row * 2], l0 = mlpart[(long)row * 2 + 1];
  float m1 = mlpart[(zs + row) * 2], l1 = mlpart[(zs + row) * 2 + 1];
  float M = fmaxf(m0, m1);
  float a0 = __expf(m0 - M), a1 = __expf(m1 - M);
  float invL = 1.f / (a0 * l0 + a1 * l1);
  a0 *= invL; a1 *= invL;
  short8 o0 = *(const short8*)&opart[(long)row * 192 + c8];
  short8 o1 = *(const short8*)&opart[zs * 192 + (long)row * 192 + c8];
  float v[8];
#pragma unroll
  for (int j = 0; j < 8; j++)
    v[j] = a0 * b2f((u16)o0[j]) + a1 * b2f((u16)o1[j]);
  uint4 oo;
  oo.x = cvtpk(v[0], v[1]);
  oo.y = cvtpk(v[2], v[3]);
  oo.z = cvtpk(v[4], v[5]);
  oo.w = cvtpk(v[6], v[7]);
  *(uint4*)&ob[((long)b * S + q) * 384 + h * 192 + c8] = oo;
}

// ============== weight convert+transpose: [K,N] f32 -> [N,K] bf16 ============
__global__ void wconv_t(const float* __restrict__ src, u16* __restrict__ dst, int K, int N) {
  __shared__ float t[32][33];
  long mb = blockIdx.z;
  src += mb * (long)K * N;
  dst += mb * (long)K * N;
  int n0 = blockIdx.x * 32, k0 = blockIdx.y * 32;
  int tx = threadIdx.x, ty = threadIdx.y;
#pragma unroll
  for (int i = 0; i < 4; i++) {
    int r = ty + i * 8;
    t[r][tx] = src[(long)(k0 + r) * N + n0 + tx];
  }
  __syncthreads();
#pragma unroll
  for (int i = 0; i < 4; i++) {
    int r = ty + i * 8;
    dst[(long)(n0 + r) * K + k0 + tx] = f2b(t[tx][r]);
  }
}

// ============== mel weight: [384][80] f32 -> [128 (pad0)][384] bf16 ==========
__global__ void melw_t(const float* __restrict__ src, u16* __restrict__ dst) {
  int i = blockIdx.x * 256 + threadIdx.x;
  if (i >= 128 * 384) return;
  int n = i / 384, kk2 = i - n * 384;
  dst[i] = (n < NMELB) ? f2b(src[(long)kk2 * NMELB + n]) : (u16)0;
}

// ============================ positional encoding ============================
__global__ void posenc_kernel(float* __restrict__ pe) {
  int i = blockIdx.x * 256 + threadIdx.x;
  if (i >= TFR * DMODEL) return;
  int t = i / DMODEL, d = i - t * DMODEL;
  float f = (2.0f * (float)(d >> 1)) / (float)DMODEL;
  float ang = (float)t * powf(10000.0f, -f);
  pe[i] = (d & 1) ? cosf(ang) : sinf(ang);
}

// ===================== embedding + scaled PE (bf16 x) ========================
__global__ void embed_kernel(const int* __restrict__ ph, const float* __restrict__ emb,
                             const float* __restrict__ pe, const float* __restrict__ alpha,
                             u16* __restrict__ xb) {
  int i = blockIdx.x * 256 + threadIdx.x;
  if (i >= BATCH * LPH * DMODEL) return;
  int d = i % DMODEL;
  int bl = i / DMODEL;
  int l = bl % LPH;
  float v = emb[ph[bl] * DMODEL + d] + alpha[0] * pe[l * DMODEL + d];
  xb[i] = f2b(v);
}

// ====== LayerNorm, vectorized: wave-per-row, C/8 active lanes x 8 elems ======
// f32 in-place (duration-predictor path).
template <int C>
__global__ __launch_bounds__(256) void lnw(float* __restrict__ x, const float* __restrict__ gamma,
                                           const float* __restrict__ beta,
                                           float* __restrict__ outf, u16* __restrict__ outb) {
  const int w = threadIdx.x >> 6, l = threadIdx.x & 63;
  const long row = (long)blockIdx.x * 4 + w;
  constexpr int NL = C / 8;
  float* xr = x + row * C;
  float v[8];
  float s1 = 0.f, s2 = 0.f;
  if (l < NL) {
    float4 a = *(const float4*)&xr[8 * l];
    float4 bq = *(const float4*)&xr[8 * l + 4];
    v[0] = a.x; v[1] = a.y; v[2] = a.z; v[3] = a.w;
    v[4] = bq.x; v[5] = bq.y; v[6] = bq.z; v[7] = bq.w;
#pragma unroll
    for (int j = 0; j < 8; j++) { s1 += v[j]; s2 += v[j] * v[j]; }
  }
#pragma unroll
  for (int off = 1; off < 64; off <<= 1) {
    s1 += __shfl_xor(s1, off);
    s2 += __shfl_xor(s2, off);
  }
  float mean = s1 / C;
  float var = s2 / C - mean * mean;
  float rstd = rsqrtf(var + 1e-6f);
  if (l < NL) {
    float4 g0 = *(const float4*)&gamma[8 * l];
    float4 g1 = *(const float4*)&gamma[8 * l + 4];
    float4 b0 = *(const float4*)&beta[8 * l];
    float4 b1 = *(const float4*)&beta[8 * l + 4];
    float o[8];
    o[0] = (v[0] - mean) * rstd * g0.x + b0.x;
    o[1] = (v[1] - mean) * rstd * g0.y + b0.y;
    o[2] = (v[2] - mean) * rstd * g0.z + b0.z;
    o[3] = (v[3] - mean) * rstd * g0.w + b0.w;
    o[4] = (v[4] - mean) * rstd * g1.x + b1.x;
    o[5] = (v[5] - mean) * rstd * g1.y + b1.y;
    o[6] = (v[6] - mean) * rstd * g1.z + b1.z;
    o[7] = (v[7] - mean) * rstd * g1.w + b1.w;
    float* tf = outf ? outf + row * C : xr;
    *(float4*)&tf[8 * l] = make_float4(o[0], o[1], o[2], o[3]);
    *(float4*)&tf[8 * l + 4] = make_float4(o[4], o[5], o[6], o[7]);
    if (outb) {
      uint4 ob4;
      ob4.x = cvtpk(o[0], o[1]);
      ob4.y = cvtpk(o[2], o[3]);
      ob4.z = cvtpk(o[4], o[5]);
      ob4.w = cvtpk(o[6], o[7]);
      *(uint4*)&outb[row * C + 8 * l] = ob4;
    }
  }
}

// ====== LayerNorm over split-K partials + bias + bf16 residual (vectorized) ==
// x = LN(b2f(p0)+b2f(p1)+bias+b2f(resb)). outb may alias resb (per-thread
// read-before-write). outf optional f32 copy (encoder final -> Henc).
template <int C>
__global__ __launch_bounds__(256) void lnsum(const u16* __restrict__ p0, const u16* __restrict__ p1,
                                             const float* __restrict__ bias,
                                             const u16* __restrict__ resb,
                                             const float* __restrict__ gamma,
                                             const float* __restrict__ beta,
                                             float* __restrict__ outf, u16* __restrict__ outb) {
  const int w = threadIdx.x >> 6, l = threadIdx.x & 63;
  const long row = (long)blockIdx.x * 4 + w;
  constexpr int NL = C / 8;
  float v[8];
  float s1 = 0.f, s2 = 0.f;
  if (l < NL) {
    short8 a = *(const short8*)&p0[row * C + 8 * l];
    short8 bq = *(const short8*)&p1[row * C + 8 * l];
    short8 r = *(const short8*)&resb[row * C + 8 * l];
    float4 bi0 = *(const float4*)&bias[8 * l];
    float4 bi1 = *(const float4*)&bias[8 * l + 4];
#pragma unroll
    for (int j = 0; j < 8; j++) {
      float bb = (j < 4) ? (&bi0.x)[j] : (&bi1.x)[j - 4];
      v[j] = b2f((u16)a[j]) + b2f((u16)bq[j]) + bb + b2f((u16)r[j]);
      s1 += v[j];
      s2 += v[j] * v[j];
    }
  }
#pragma unroll
  for (int off = 1; off < 64; off <<= 1) {
    s1 += __shfl_xor(s1, off);
    s2 += __shfl_xor(s2, off);
  }
  float mean = s1 / C;
  float var = s2 / C - mean * mean;
  float rstd = rsqrtf(var + 1e-6f);
  if (l < NL) {
    float4 g0 = *(const float4*)&gamma[8 * l];
    float4 g1 = *(const float4*)&gamma[8 * l + 4];
    float4 b0 = *(const float4*)&beta[8 * l];
    float4 b1 = *(const float4*)&beta[8 * l + 4];
    float o[8];
    o[0] = (v[0] - mean) * rstd * g0.x + b0.x;
    o[1] = (v[1] - mean) * rstd * g0.y + b0.y;
    o[2] = (v[2] - mean) * rstd * g0.z + b0.z;
    o[3] = (v[3] - mean) * rstd * g0.w + b0.w;
    o[4] = (v[4] - mean) * rstd * g1.x + b1.x;
    o[5] = (v[5] - mean) * rstd * g1.y + b1.y;
    o[6] = (v[6] - mean) * rstd * g1.z + b1.z;
    o[7] = (v[7] - mean) * rstd * g1.w + b1.w;
    if (outf) {
      *(float4*)&outf[row * C + 8 * l] = make_float4(o[0], o[1], o[2], o[3]);
      *(float4*)&outf[row * C + 8 * l + 4] = make_float4(o[4], o[5], o[6], o[7]);
    }
    if (outb) {
      uint4 ob4;
      ob4.x = cvtpk(o[0], o[1]);
      ob4.y = cvtpk(o[2], o[3]);
      ob4.z = cvtpk(o[4], o[5]);
      ob4.w = cvtpk(o[6], o[7]);
      *(uint4*)&outb[row * C + 8 * l] = ob4;
    }
  }
}

// ==================== im2col for K=3 SAME conv (f32 -> bf16) =================
template <int CIN>
__global__ __launch_bounds__(256) void im2col3(const float* __restrict__ x,
                                               u16* __restrict__ a) {
  const int PER = (3 * CIN) / 8;
  long idx = (long)blockIdx.x * 256 + threadIdx.x;
  if (idx >= (long)BATCH * LPH * PER) return;
  int row = (int)(idx / PER);
  int e8 = (int)(idx - (long)row * PER) * 8;
  int kk = e8 / CIN, ci = e8 - kk * CIN;
  int b = row >> 7, l = row & (LPH - 1);
  int gl = l + kk - 1;
  ushort4 o0 = {0, 0, 0, 0}, o1 = {0, 0, 0, 0};
  if (gl >= 0 && gl < LPH) {
    const float* src = x + ((long)(b * LPH + gl) * CIN + ci);
    float4 v0 = *(const float4*)src;
    float4 v1 = *(const float4*)(src + 4);
    o0.x = f2b(v0.x); o0.y = f2b(v0.y); o0.z = f2b(v0.z); o0.w = f2b(v0.w);
    o1.x = f2b(v1.x); o1.y = f2b(v1.y); o1.z = f2b(v1.z); o1.w = f2b(v1.w);
  }
  *(ushort4*)&a[(long)row * (3 * CIN) + e8] = o0;
  *(ushort4*)&a[(long)row * (3 * CIN) + e8 + 4] = o1;
}

// ============================ duration projection ============================
__global__ void dpout_kernel(const float* __restrict__ d2, const float* __restrict__ w,
                             const float* __restrict__ bb, float* __restrict__ out) {
  int wv = threadIdx.x >> 6, lane = threadIdx.x & 63;
  int row = blockIdx.x * 4 + wv;
  const float* xr = d2 + (long)row * CDPC;
  float s = 0.f;
  for (int c = lane; c < CDPC; c += 64) s = fmaf(xr[c], w[c], s);
#pragma unroll
  for (int off = 32; off > 0; off >>= 1) s += __shfl_down(s, off);
  if (lane == 0) out[row] = s + bb[0];
}

// ============================ length regulator ===============================
__global__ void regulator_kernel(const int* __restrict__ durations, int* __restrict__ idx,
                                 float* __restrict__ maskv, float* __restrict__ maska) {
  __shared__ int cum[LPH];
  __shared__ int total;
  int b = blockIdx.x;
  if (threadIdx.x == 0) {
    int s = 0;
    for (int j = 0; j < LPH; j++) { s += durations[b * LPH + j]; cum[j] = s; }
    total = s;
  }
  __syncthreads();
  for (int t = threadIdx.x; t < TFR; t += blockDim.x) {
    int cnt = 0;
    for (int j = 0; j < LPH; j++) cnt += (cum[j] <= t) ? 1 : 0;
    if (cnt > LPH - 1) cnt = LPH - 1;
    idx[b * TFR + t] = cnt;
    maskv[b * TFR + t] = (t < total) ? 0.f : 1.f;   // 1 = masked (multiplicative)
    maska[b * TFR + t] = (t < total) ? 0.f : NEGV;  // additive logit bias
  }
}

// gather expanded states, apply valid mask, add scaled PE (bf16 out)
__global__ void gather_kernel(const float* __restrict__ h, const int* __restrict__ idx,
                              const float* __restrict__ maskv, const float* __restrict__ pe,
                              const float* __restrict__ alpha, u16* __restrict__ yb) {
  long i = (long)blockIdx.x * 256 + threadIdx.x;
  if (i >= (long)BATCH * TFR * DMODEL) return;
  int d = (int)(i % DMODEL);
  long bt = i / DMODEL;
  int t = (int)(bt % TFR);
  long b = bt / TFR;
  float valid = 1.0f - maskv[bt];
  float v = h[((long)b * LPH + idx[bt]) * DMODEL + d] * valid + alpha[0] * pe[t * DMODEL + d];
  yb[i] = f2b(v);
}

// ============================ launcher =======================================
extern "C" void kernel_launch(void* const* d_in, const int* in_sizes, int n_in,
                              void* d_out, int out_size, void* d_ws, size_t ws_size,
                              hipStream_t stream) {
  const int* phonemes = (const int*)d_in[0];
  const int* durations = (const int*)d_in[1];
  const float* embedw = (const float*)d_in[2];
  const float* alpha_enc = (const float*)d_in[3];
  const float* alpha_dec = (const float*)d_in[4];
  const float* enc_attn_w = (const float*)d_in[5];
  const float* enc_attn_b = (const float*)d_in[6];
  const float* enc_ffn_w1 = (const float*)d_in[7];
  const float* enc_ffn_b1 = (const float*)d_in[8];
  const float* enc_ffn_w2 = (const float*)d_in[9];
  const float* enc_ffn_b2 = (const float*)d_in[10];
  const float* enc_ln = (const float*)d_in[11];
  const float* dec_attn_w = (const float*)d_in[12];
  const float* dec_attn_b = (const float*)d_in[13];
  const float* dec_ffn_w1 = (const float*)d_in[14];
  const float* dec_ffn_b1 = (const float*)d_in[15];
  const float* dec_ffn_w2 = (const float*)d_in[16];
  const float* dec_ffn_b2 = (const float*)d_in[17];
  const float* dec_ln = (const float*)d_in[18];
  const float* dp_conv1_w = (const float*)d_in[19];
  const float* dp_conv1_b = (const float*)d_in[20];
  const float* dp_conv2_w = (const float*)d_in[21];
  const float* dp_conv2_b = (const float*)d_in[22];
  const float* dp_ln = (const float*)d_in[23];
  const float* dp_out_w = (const float*)d_in[24];
  const float* dp_out_b = (const float*)d_in[25];
  const float* mel_w = (const float*)d_in[26];
  const float* mel_b = (const float*)d_in[27];

  // ---- workspace map (bytes). Post-LN: residual carrier == Xb (bf16). ----
  char* base = (char*)d_ws;
  u16* FP = (u16*)base;                        // 25,165,824  FFN2 split-K partials
  u16* Xb = (u16*)(base + 25165824);           // 12,582,912  bf16 x (LN out = residual)
  u16* QKb = (u16*)(base + 37748736);          // 25,165,824  q, k (AOb/Mb overlay)
  char* E = base + 62914560;                   // 33,554,432  attn/AO partials, DP scratch
  u16* Vt = (u16*)(base + 96468992);           // 16,777,216  V^T [32][256][S]
  u16* Wb = (u16*)(base + 113246208);          // 21,233,664  bf16 weights (per stack)
  float* Henc = (float*)(base + 134479872);    // 3,145,728   encoder output h (f32)
  float* PE = (float*)(base + 137625600);      // 1,572,864
  float* MASKD = (float*)(base + 139198464);   // 65,536
  int* IDX = (int*)(base + 139264000);         // 65,536
  u16* Wmel = (u16*)(base + 139329536);        // 98,304      [128][384] bf16
  float* MASKA = (float*)(base + 139427840);   // 65,536      additive mask

  u16* AOb = QKb;
  u16* Mb = QKb;  // FFN mid overlays q/k/attn-out (dead by then)

  // attention split-K partials + AO partials in E (phase-disjoint)
  u16* OPART = (u16*)E;
  float* MLPART = (float*)(E + 25165824);
  u16* AOP = (u16*)E;

  // duration-predictor overlays in E
  float* DP1 = (float*)E;
  float* DP2 = DP1 + (size_t)2048 * CDPC;
  u16* A1 = (u16*)(E + 4 * 1024 * 1024);
  u16* A2 = (u16*)(E + 9 * 1024 * 1024);
  u16* Wdp1 = (u16*)(E + 13 * 1024 * 1024);
  u16* Wdp2 = (u16*)(E + 15 * 1024 * 1024);

  u16* WAt = Wb;                 // 24 x [384][384]
  u16* W1t = Wb + 3538944;       // 6 x [1536][384]
  u16* W2t = Wb + 7077888;       // 6 x [384][1536]

  const int Me = BATCH * LPH;    // 2048
  const int Md = BATCH * TFR;    // 16384
  const long DD = 384L * 384;
  const long NXe = (long)Me * DMODEL;   // 786,432
  const long NXd = (long)Md * DMODEL;   // 6,291,456
  dim3 tb32(32, 8);

  posenc_kernel<<<(TFR * DMODEL + 255) / 256, 256, 0, stream>>>(PE);
  embed_kernel<<<(Me * DMODEL + 255) / 256, 256, 0, stream>>>(phonemes, embedw, PE, alpha_enc, Xb);
  wconv_t<<<dim3(12, 12, 24), tb32, 0, stream>>>(enc_attn_w, WAt, 384, 384);
  wconv_t<<<dim3(48, 12, 6), tb32, 0, stream>>>(enc_ffn_w1, W1t, 384, 1536);
  wconv_t<<<dim3(12, 48, 6), tb32, 0, stream>>>(enc_ffn_w2, W2t, 1536, 384);
  melw_t<<<192, 256, 0, stream>>>(mel_w, Wmel);

  // -------- phoneme encoder (x stream in Xb only) --------
  for (int i = 0; i < NLAYER; i++) {
    const u16* wa = WAt + (size_t)i * 4 * DD;
    const float* ab = enc_attn_b + (size_t)i * 4 * 384;
    bgemm<(FBIAS | FOB16 | FVT)><<<dim3(3, 16, 3), 256, 0, stream>>>(
        Xb, wa, ab, nullptr, QKb, Vt, 384, 384, 384, 384, 384,
        1, 0, 0, DD, 0, NXe, 0, 128);
    fattn<<<dim3(1, 32, 2), 512, 0, stream>>>(QKb, QKb + NXe, Vt, nullptr, OPART, MLPART, 128, 0);
    fmerge<<<384, 256, 0, stream>>>(OPART, MLPART, AOb, 128);
    bgemm<(FOB16)><<<dim3(3, 16, 2), 256, 0, stream>>>(
        AOb, wa + 3 * DD, nullptr, nullptr, AOP, nullptr, 384, 192, 384, 384, 384,
        2, 0, 192, 0, 192, 0, NXe, 0);
    lnsum<384><<<Me / 4, 256, 0, stream>>>(AOP, AOP + NXe, ab + 3 * 384, Xb,
                                           enc_ln + ((size_t)(i * 2 + 0) * 2 + 0) * 384,
                                           enc_ln + ((size_t)(i * 2 + 0) * 2 + 1) * 384,
                                           nullptr, Xb);
    bgemm<(FBIAS | FRELU | FOB16)><<<dim3(12, 16, 1), 256, 0, stream>>>(
        Xb, W1t + (size_t)i * 589824, enc_ffn_b1 + (size_t)i * 1536, nullptr, Mb, nullptr,
        1536, 384, 384, 384, 1536, 1, 0, 0, 0, 0, 0, 0, 0);
    bgemm<(FOB16)><<<dim3(3, 16, 2), 256, 0, stream>>>(
        Mb, W2t + (size_t)i * 589824, nullptr, nullptr, FP, nullptr,
        384, 768, 1536, 1536, 384, 2, 0, 768, 0, 768, 0, NXe, 0);
    lnsum<384><<<Me / 4, 256, 0, stream>>>(FP, FP + NXe, enc_ffn_b2 + (size_t)i * 384, Xb,
                                           enc_ln + ((size_t)(i * 2 + 1) * 2 + 0) * 384,
                                           enc_ln + ((size_t)(i * 2 + 1) * 2 + 1) * 384,
                                           (i == NLAYER - 1) ? Henc : nullptr, Xb);
  }

  // -------- duration predictor (h = Henc) via im2col + bf16 GEMM --------
  wconv_t<<<dim3(8, 36, 1), tb32, 0, stream>>>(dp_conv1_w, Wdp1, 1152, 256);
  wconv_t<<<dim3(8, 24, 1), tb32, 0, stream>>>(dp_conv2_w, Wdp2, 768, 256);
  im2col3<DMODEL><<<(Me * 144 + 255) / 256, 256, 0, stream>>>(Henc, A1);
  bgemm<(FBIAS | FRELU)><<<dim3(2, 16, 1), 256, 0, stream>>>(
      A1, Wdp1, dp_conv1_b, nullptr, DP1, nullptr, 256, 1152, 1152, 1152, 256,
      1, 0, 0, 0, 0, 0, 0, 0);
  lnw<256><<<Me / 4, 256, 0, stream>>>(DP1, dp_ln + 0 * CDPC, dp_ln + 1 * CDPC, nullptr, nullptr);
  im2col3<CDPC><<<(Me * 96 + 255) / 256, 256, 0, stream>>>(DP1, A2);
  bgemm<(FBIAS | FRELU)><<<dim3(2, 16, 1), 256, 0, stream>>>(
      A2, Wdp2, dp_conv2_b, nullptr, DP2, nullptr, 256, 768, 768, 768, 256,
      1, 0, 0, 0, 0, 0, 0, 0);
  lnw<256><<<Me / 4, 256, 0, stream>>>(DP2, dp_ln + 2 * CDPC, dp_ln + 3 * CDPC, nullptr, nullptr);
  float* durout = (float*)d_out + (size_t)Md * NMELB;
  dpout_kernel<<<Me / 4, 256, 0, stream>>>(DP2, dp_out_w, dp_out_b, durout);

  // -------- length regulator --------
  regulator_kernel<<<BATCH, 256, 0, stream>>>(durations, IDX, MASKD, MASKA);
  gather_kernel<<<(int)((NXd + 255) / 256), 256, 0, stream>>>(Henc, IDX, MASKD, PE, alpha_dec, Xb);
  wconv_t<<<dim3(12, 12, 24), tb32, 0, stream>>>(dec_attn_w, WAt, 384, 384);
  wconv_t<<<dim3(48, 12, 6), tb32, 0, stream>>>(dec_ffn_w1, W1t, 384, 1536);
  wconv_t<<<dim3(12, 48, 6), tb32, 0, stream>>>(dec_ffn_w2, W2t, 1536, 384);

  // -------- mel decoder --------
  for (int i = 0; i < NLAYER; i++) {
    const u16* wa = WAt + (size_t)i * 4 * DD;
    const float* ab = dec_attn_b + (size_t)i * 4 * 384;
    bgemm<(FBIAS | FOB16 | FVT)><<<dim3(3, 128, 3), 256, 0, stream>>>(
        Xb, wa, ab, nullptr, QKb, Vt, 384, 384, 384, 384, 384,
        1, 0, 0, DD, 0, NXd, 0, 1024);
    fattn<<<dim3(8, 32, 2), 512, 0, stream>>>(QKb, QKb + NXd, Vt, MASKA, OPART, MLPART, 1024, 3);
    fmerge<<<3072, 256, 0, stream>>>(OPART, MLPART, AOb, 1024);
    bgemm<(FOB16)><<<dim3(3, 128, 2), 256, 0, stream>>>(
        AOb, wa + 3 * DD, nullptr, nullptr, AOP, nullptr, 384, 192, 384, 384, 384,
        2, 0, 192, 0, 192, 0, NXd, 0);
    lnsum<384><<<Md / 4, 256, 0, stream>>>(AOP, AOP + NXd, ab + 3 * 384, Xb,
                                           dec_ln + ((size_t)(i * 2 + 0) * 2 + 0) * 384,
                                           dec_ln + ((size_t)(i * 2 + 0) * 2 + 1) * 384,
                                           nullptr, Xb);
    bgemm<(FBIAS | FRELU | FOB16)><<<dim3(12, 128, 1), 256, 0, stream>>>(
        Xb, W1t + (size_t)i * 589824, dec_ffn_b1 + (size_t)i * 1536, nullptr, Mb, nullptr,
        1536, 384, 384, 384, 1536, 1, 0, 0, 0, 0, 0, 0, 0);
    bgemm<(FOB16)><<<dim3(3, 128, 2), 256, 0, stream>>>(
        Mb, W2t + (size_t)i * 589824, nullptr, nullptr, FP, nullptr,
        384, 768, 1536, 1536, 384, 2, 0, 768, 0, 768, 0, NXd, 0);
    lnsum<384><<<Md / 4, 256, 0, stream>>>(FP, FP + NXd, dec_ffn_b2 + (size_t)i * 384, Xb,
                                           dec_ln + ((size_t)(i * 2 + 1) * 2 + 0) * 384,
                                           dec_ln + ((size_t)(i * 2 + 1) * 2 + 1) * 384,
                                           nullptr, Xb);
  }

  // -------- mel projection (bf16 MFMA, N=80 padded to 128) --------
  bgemm<(FBIAS)><<<dim3(1, 128, 1), 256, 0, stream>>>(
      Xb, Wmel, mel_b, nullptr, (float*)d_out, nullptr, 80, 384, 384, 384, 80,
      1, 0, 0, 0, 0, 0, 0, 0);
}